// Round 2
// baseline (1143.315 us; speedup 1.0000x reference)
//
#include <hip/hip_runtime.h>

// NaryTreeLSTMCell: B=32, L=512, E=H=1024.  Outputs h_out, c_out (f32, 2x16384x1024).
//
// Math (from the reference):
//   gx = x @ [W_ioux | W_fx]                      -> [16384][4096] (cols: i,o,u,fx)
//   gh = h0 @ [Wiouh0[:, :H] | Wiouh1[:, :H] | Wfh0+Wfh1 | Wfh2+Wfh3] + bias
//                                                 -> [16384][4096] (cols: hr_i,hl_i,fr,fl)
//   addb = scatter_add(gh[:, 0:1024], idr) + scatter_add(gh[:,1024:2048], idl)
//   f    = sigmoid(gather(gx[:,3072:],idd) + gather(gh[:,2048:3072],idr) + gather(gh[:,3072:],idl))
//   fcb  = scatter_add(f * c0, idd)
//   i,o,u = sig(gx_i+addb), sig(gx_o), tanh(gx_u);  c_new = i*u + fcb;  h_new = o*tanh(c_new)
//   masked_scatter == compaction: k-th selected row (idd!=0, flat order) <- h_new/c_new row k.
//
// Workspace is ADAPTIVE: fixed 17 MB (bf16 weight panels + bias + sel) plus per-chunk
// buffers of 14 MB per batch; chunk size C = largest divisor of 32 fitting ws_size.
// All scatters/gathers are intra-batch, and compaction needs only global sel[]/m,
// so batch-chunking is exact.

#define ROWS 16384   // B*L
#define HID  1024
#define KDIM 1024
#define NCOLS 4096
#define TM 128
#define TN 128
#define TK 32

typedef __attribute__((ext_vector_type(4))) int            i32x4;
typedef __attribute__((ext_vector_type(4))) float          f32x4;
typedef __attribute__((ext_vector_type(4))) unsigned short u16x4;

__device__ __forceinline__ unsigned short f2bf(float f) {
  unsigned u = __float_as_uint(f);
  unsigned r = 0x7FFFu + ((u >> 16) & 1u);
  return (unsigned short)((u + r) >> 16);
}
__device__ __forceinline__ float bf2f(unsigned short v) {
  return __uint_as_float(((unsigned)v) << 16);
}
__device__ __forceinline__ float sigmoidf_(float x) {
  return 1.0f / (1.0f + __expf(-x));
}
__device__ __forceinline__ void gload16(const void* g, void* l) {
  __builtin_amdgcn_global_load_lds(
      (const __attribute__((address_space(1))) void*)g,
      (__attribute__((address_space(3))) void*)l, 16, 0, 0);
}
// A and B fragments use the SAME (lane,elem)->k storage mapping, so any HW
// k-permutation cancels in the dot product (m97-verified structure).
__device__ __forceinline__ void mfma_bf16(f32x4& acc, i32x4 a, i32x4 b) {
  asm volatile("v_mfma_f32_16x16x32_bf16 %0, %1, %2, %0"
               : "+v"(acc) : "v"(a), "v"(b));
}

// ---- weight packing: transposed bf16 panels [N=4096][K=1024] ----

__global__ void pack_wx(const float* __restrict__ Wioux, const float* __restrict__ Wfx,
                        unsigned short* __restrict__ Wxt) {
  __shared__ float t[32][33];
  const int n0 = blockIdx.x * 32, k0 = blockIdx.y * 32;
  const int tx = threadIdx.x, ty = threadIdx.y;
  const int n = n0 + tx, k = k0 + ty;
  float v = (n < 3072) ? Wioux[(size_t)k * 3072 + n]
                       : Wfx[(size_t)k * 1024 + (n - 3072)];
  t[ty][tx] = v;
  __syncthreads();
  Wxt[(size_t)(n0 + ty) * KDIM + (k0 + tx)] = f2bf(t[tx][ty]);
}

__global__ void pack_wh(const float* __restrict__ Wiouh, const float* __restrict__ Wfh,
                        unsigned short* __restrict__ Wht) {
  __shared__ float t[32][33];
  const int n0 = blockIdx.x * 32, k0 = blockIdx.y * 32;
  const int tx = threadIdx.x, ty = threadIdx.y;
  const int n = n0 + tx, k = k0 + ty;
  float v;
  if (n < 1024)      v = Wiouh[(size_t)k * 3072 + n];
  else if (n < 2048) v = Wiouh[3145728u + (size_t)k * 3072 + (n - 1024)];
  else if (n < 3072) { const int c = n - 2048;
    v = Wfh[(size_t)k * 1024 + c] + Wfh[1048576u + (size_t)k * 1024 + c]; }
  else { const int c = n - 3072;
    v = Wfh[2097152u + (size_t)k * 1024 + c] + Wfh[3145728u + (size_t)k * 1024 + c]; }
  t[ty][tx] = v;
  __syncthreads();
  Wht[(size_t)(n0 + ty) * KDIM + (k0 + tx)] = f2bf(t[tx][ty]);
}

__global__ void pack_bias(const float* __restrict__ b_iouh, const float* __restrict__ b_fh,
                          float* __restrict__ bh) {
  const int n = blockIdx.x * 1024 + threadIdx.x;
  float v;
  if (n < 1024)      v = b_iouh[n];
  else if (n < 2048) v = b_iouh[3072 + (n - 1024)];
  else if (n < 3072) { const int c = n - 2048; v = b_fh[c] + b_fh[1024 + c]; }
  else { const int c = n - 3072; v = b_fh[2048 + c] + b_fh[3072 + c]; }
  bh[n] = v;
}

// chunked: converts R*1024 elems of x and h0 (pointers pre-offset to chunk start)
__global__ void convert_bf16(const float* __restrict__ x, const float* __restrict__ h0,
                             unsigned short* __restrict__ xb, unsigned short* __restrict__ hb) {
  const size_t i = ((size_t)blockIdx.x * 256 + threadIdx.x) * 4;
  const float4 a = *(const float4*)&x[i];
  const float4 b = *(const float4*)&h0[i];
  u16x4 av = { f2bf(a.x), f2bf(a.y), f2bf(a.z), f2bf(a.w) };
  u16x4 bv = { f2bf(b.x), f2bf(b.y), f2bf(b.z), f2bf(b.w) };
  *(u16x4*)&xb[i] = av;
  *(u16x4*)&hb[i] = bv;
}

__global__ void zero_ws(float4* __restrict__ p) {
  const size_t i = (size_t)blockIdx.x * 256 + threadIdx.x;
  p[i] = make_float4(0.f, 0.f, 0.f, 0.f);
}

// ---- GEMM (m97 structure): 128x128 tile, BK=32, 4 waves, global_load_lds w16.
// A [R][1024] bf16, Bt [4096][1024] bf16, out bf16 [R][4096]. grid.z: 0=x-side, 1=h-side.
__global__ __launch_bounds__(256)
void gemm_both(const unsigned short* __restrict__ xb, const unsigned short* __restrict__ hb,
               const unsigned short* __restrict__ Wxt, const unsigned short* __restrict__ Wht,
               unsigned short* __restrict__ gxb, unsigned short* __restrict__ ghb,
               const float* __restrict__ bhv) {
  __shared__ __align__(16) unsigned short As[TM * TK];
  __shared__ __align__(16) unsigned short Bs[TN * TK];

  const unsigned short* A;
  const unsigned short* Bt;
  unsigned short* Cp;
  const float* bias;
  if (blockIdx.z == 0) { A = xb; Bt = Wxt; Cp = gxb; bias = nullptr; }
  else                 { A = hb; Bt = Wht; Cp = ghb; bias = bhv; }

  const int tid = threadIdx.x;
  const int w = tid >> 6, lane = tid & 63;
  const int bm = blockIdx.y * TM, bn = blockIdx.x * TN;
  const int wm = (w & 1) * 64, wn = (w >> 1) * 64;
  const int m0 = lane & 15, kg = lane >> 4;

  // staging: wave w loads 16 rows of A and of Bt; lane -> (row=l>>2, 16B seg=l&3)
  const int srow = w * 16 + (lane >> 2);
  const int sseg = (lane & 3) * 8;
  const unsigned short* ga0 = A  + (size_t)(bm + srow) * KDIM + sseg;
  const unsigned short* ga1 = ga0 + (size_t)64 * KDIM;
  const unsigned short* gb0 = Bt + (size_t)(bn + srow) * KDIM + sseg;
  const unsigned short* gb1 = gb0 + (size_t)64 * KDIM;
  unsigned short* la0 = &As[(w * 16) * TK];        // wave-uniform LDS bases
  unsigned short* la1 = &As[(64 + w * 16) * TK];
  unsigned short* lb0 = &Bs[(w * 16) * TK];
  unsigned short* lb1 = &Bs[(64 + w * 16) * TK];

  const int aoff = (wm + m0) * TK + kg * 8;
  const int boff = (wn + m0) * TK + kg * 8;

  f32x4 acc[4][4] = {};

  for (int k0 = 0; k0 < KDIM; k0 += TK) {
    gload16(ga0 + k0, la0);
    gload16(ga1 + k0, la1);
    gload16(gb0 + k0, lb0);
    gload16(gb1 + k0, lb1);
    __syncthreads();
    i32x4 af[4], bf[4];
#pragma unroll
    for (int i = 0; i < 4; ++i) af[i] = *(const i32x4*)&As[aoff + i * 16 * TK];
#pragma unroll
    for (int j = 0; j < 4; ++j) bf[j] = *(const i32x4*)&Bs[boff + j * 16 * TK];
#pragma unroll
    for (int i = 0; i < 4; ++i)
#pragma unroll
      for (int j = 0; j < 4; ++j)
        mfma_bf16(acc[i][j], af[i], bf[j]);
    __syncthreads();
  }

  // C/D layout (m89/m91): col = lane&15, row = 4*(lane>>4) + reg
  const int rg = (lane >> 4) * 4;
#pragma unroll
  for (int i = 0; i < 4; ++i) {
#pragma unroll
    for (int j = 0; j < 4; ++j) {
      const int col = bn + wn + j * 16 + m0;
      const float bv = bias ? bias[col] : 0.0f;
      const int row = bm + wm + i * 16 + rg;
#pragma unroll
      for (int r = 0; r < 4; ++r)
        Cp[(size_t)(row + r) * NCOLS + col] = f2bf(acc[i][j][r] + bv);
    }
  }
}

// ---- global mask compaction scan: sel[k] = flat row index of k-th selected row ----
__global__ void scan_mask(const int* __restrict__ idd, int* __restrict__ sel,
                          int* __restrict__ mcount) {
  __shared__ int ps[1024];
  const int t = threadIdx.x;
  int loc[16];
  int cnt = 0;
#pragma unroll
  for (int i = 0; i < 16; ++i) {
    const int v = (idd[t * 16 + i] != 0) ? 1 : 0;
    loc[i] = v; cnt += v;
  }
  ps[t] = cnt;
  __syncthreads();
  for (int off = 1; off < 1024; off <<= 1) {
    const int add = (t >= off) ? ps[t - off] : 0;
    __syncthreads();
    ps[t] += add;
    __syncthreads();
  }
  int rank = (t == 0) ? 0 : ps[t - 1];
#pragma unroll
  for (int i = 0; i < 16; ++i)
    if (loc[i]) sel[rank++] = t * 16 + i;
  if (t == 1023) *mcount = ps[1023];
}

// ---- chunk-local: scatter gh cols 0:2048 into addb (i-gate additions) ----
__global__ void scatter_hrhl(const unsigned short* __restrict__ ghb,
                             const int* __restrict__ idr, const int* __restrict__ idl,
                             float* __restrict__ addb) {
  const int row = blockIdx.x;            // local row in chunk
  const int c = threadIdx.x << 2;
  const int bl = row >> 9;
  const int jr = idr[row], jl = idl[row];
  const u16x4 hr = *(const u16x4*)&ghb[(size_t)row * NCOLS + c];
  const u16x4 hl = *(const u16x4*)&ghb[(size_t)row * NCOLS + 1024 + c];
  float* dr = &addb[((size_t)(bl << 9) + jr) * HID + c];
  float* dl = &addb[((size_t)(bl << 9) + jl) * HID + c];
  atomicAdd(dr + 0, bf2f(hr[0])); atomicAdd(dr + 1, bf2f(hr[1]));
  atomicAdd(dr + 2, bf2f(hr[2])); atomicAdd(dr + 3, bf2f(hr[3]));
  atomicAdd(dl + 0, bf2f(hl[0])); atomicAdd(dl + 1, bf2f(hl[1]));
  atomicAdd(dl + 2, bf2f(hl[2])); atomicAdd(dl + 3, bf2f(hl[3]));
}

// ---- chunk-local: f-gate gather + fc scatter (c0 pointer pre-offset to chunk) ----
__global__ void f_fc(const unsigned short* __restrict__ gxb, const unsigned short* __restrict__ ghb,
                     const float* __restrict__ c0c, const int* __restrict__ idd,
                     const int* __restrict__ idr, const int* __restrict__ idl,
                     float* __restrict__ fcb) {
  const int row = blockIdx.x;
  const int c = threadIdx.x << 2;
  const int base = (row >> 9) << 9;
  const size_t rd = (size_t)(base + idd[row]);
  const size_t rr = (size_t)(base + idr[row]);
  const size_t rl = (size_t)(base + idl[row]);
  const u16x4 a  = *(const u16x4*)&gxb[rd * NCOLS + 3072 + c];
  const u16x4 r_ = *(const u16x4*)&ghb[rr * NCOLS + 2048 + c];
  const u16x4 l_ = *(const u16x4*)&ghb[rl * NCOLS + 3072 + c];
  const float4 cc = *(const float4*)&c0c[(size_t)row * HID + c];
  const float f0 = sigmoidf_(bf2f(a[0]) + bf2f(r_[0]) + bf2f(l_[0])) * cc.x;
  const float f1 = sigmoidf_(bf2f(a[1]) + bf2f(r_[1]) + bf2f(l_[1])) * cc.y;
  const float f2 = sigmoidf_(bf2f(a[2]) + bf2f(r_[2]) + bf2f(l_[2])) * cc.z;
  const float f3 = sigmoidf_(bf2f(a[3]) + bf2f(r_[3]) + bf2f(l_[3])) * cc.w;
  float* d = &fcb[rd * HID + c];
  atomicAdd(d + 0, f0); atomicAdd(d + 1, f1);
  atomicAdd(d + 2, f2); atomicAdd(d + 3, f3);
}

// ---- chunk-local activations + global compaction write ----
__global__ void final_k(const unsigned short* __restrict__ gxb, const float* __restrict__ addb,
                        const float* __restrict__ fcb, const float* __restrict__ h0,
                        const float* __restrict__ c0, const int* __restrict__ idd_c,
                        const int* __restrict__ sel, const int* __restrict__ mcount,
                        float* __restrict__ hout, float* __restrict__ cout, int r0) {
  const int r = blockIdx.x;              // local row
  const int c = threadIdx.x << 2;
  const int g = r0 + r;                  // global flat row
  if (idd_c[r] == 0) {                   // unselected output rows keep h0/c0
    *(float4*)&hout[(size_t)g * HID + c] = *(const float4*)&h0[(size_t)g * HID + c];
    *(float4*)&cout[(size_t)g * HID + c] = *(const float4*)&c0[(size_t)g * HID + c];
  }
  const int m = *mcount;
  if (g < m) {                           // h_new/c_new flat row g lands at out row sel[g]
    const int j = sel[g];
    const u16x4 vi = *(const u16x4*)&gxb[(size_t)r * NCOLS + c];
    const u16x4 vo = *(const u16x4*)&gxb[(size_t)r * NCOLS + 1024 + c];
    const u16x4 vu = *(const u16x4*)&gxb[(size_t)r * NCOLS + 2048 + c];
    const float4 ad = *(const float4*)&addb[(size_t)r * HID + c];
    const float4 fc = *(const float4*)&fcb[(size_t)r * HID + c];
    float4 hn, cn;
    {
      const float ig = sigmoidf_(bf2f(vi[0]) + ad.x), og = sigmoidf_(bf2f(vo[0]));
      const float ug = tanhf(bf2f(vu[0]));
      cn.x = ig * ug + fc.x; hn.x = og * tanhf(cn.x);
    }
    {
      const float ig = sigmoidf_(bf2f(vi[1]) + ad.y), og = sigmoidf_(bf2f(vo[1]));
      const float ug = tanhf(bf2f(vu[1]));
      cn.y = ig * ug + fc.y; hn.y = og * tanhf(cn.y);
    }
    {
      const float ig = sigmoidf_(bf2f(vi[2]) + ad.z), og = sigmoidf_(bf2f(vo[2]));
      const float ug = tanhf(bf2f(vu[2]));
      cn.z = ig * ug + fc.z; hn.z = og * tanhf(cn.z);
    }
    {
      const float ig = sigmoidf_(bf2f(vi[3]) + ad.w), og = sigmoidf_(bf2f(vo[3]));
      const float ug = tanhf(bf2f(vu[3]));
      cn.w = ig * ug + fc.w; hn.w = og * tanhf(cn.w);
    }
    *(float4*)&hout[(size_t)j * HID + c] = hn;
    *(float4*)&cout[(size_t)j * HID + c] = cn;
  }
}

extern "C" void kernel_launch(void* const* d_in, const int* in_sizes, int n_in,
                              void* d_out, int out_size, void* d_ws, size_t ws_size,
                              hipStream_t stream) {
  const float* x      = (const float*)d_in[0];
  const float* h0     = (const float*)d_in[1];
  const float* c0     = (const float*)d_in[2];
  const float* W_ioux = (const float*)d_in[3];
  const float* W_iouh = (const float*)d_in[4];
  const float* b_iouh = (const float*)d_in[5];
  const float* W_fx   = (const float*)d_in[6];
  const float* W_fh   = (const float*)d_in[7];
  const float* b_fh   = (const float*)d_in[8];
  const int* idd      = (const int*)d_in[9];
  const int* idr      = (const int*)d_in[10];
  const int* idl      = (const int*)d_in[11];
  float* hout = (float*)d_out;
  float* cout = hout + (size_t)ROWS * HID;

  // fixed region: 17 MB
  char* ws = (char*)d_ws;
  unsigned short* Wxt  = (unsigned short*)(ws);              // 8 MB
  unsigned short* Wht  = (unsigned short*)(ws + 8388608u);   // 8 MB
  float*          bh   = (float*)(ws + 16777216u);           // 16 KB
  int*            sel  = (int*)(ws + 16793600u);             // 64 KB
  int*            mcnt = (int*)(ws + 16859136u);             // 4 B
  const size_t    base = 16859392u;

  // chunk size: largest divisor of 32 whose buffers fit ws_size (14 MB per batch)
  int C = 32;
  while (C > 1 && base + 14680064ull * (size_t)C > ws_size) C >>= 1;
  const int R = 512 * C;  // rows per chunk

  char* p = ws + base;
  unsigned short* xb  = (unsigned short*)p;  p += 1048576ull * C;
  unsigned short* hb  = (unsigned short*)p;  p += 1048576ull * C;
  unsigned short* gxb = (unsigned short*)p;  p += 4194304ull * C;
  unsigned short* ghb = (unsigned short*)p;  p += 4194304ull * C;
  float*          addb = (float*)p;          p += 2097152ull * C;
  float*          fcb  = (float*)p;          // contiguous with addb (zeroed together)

  pack_wx<<<dim3(128, 32), dim3(32, 32), 0, stream>>>(W_ioux, W_fx, Wxt);
  pack_wh<<<dim3(128, 32), dim3(32, 32), 0, stream>>>(W_iouh, W_fh, Wht);
  pack_bias<<<4, 1024, 0, stream>>>(b_iouh, b_fh, bh);
  scan_mask<<<1, 1024, 0, stream>>>(idd, sel, mcnt);

  for (int b0 = 0; b0 < 32; b0 += C) {
    const size_t r0 = (size_t)b0 * 512;
    convert_bf16<<<R, 256, 0, stream>>>(x + r0 * HID, h0 + r0 * HID, xb, hb);
    zero_ws<<<1024 * C, 256, 0, stream>>>((float4*)addb);   // addb+fcb = 4 MB*C contiguous
    gemm_both<<<dim3(NCOLS / TN, R / TM, 2), 256, 0, stream>>>(xb, hb, Wxt, Wht, gxb, ghb, bh);
    scatter_hrhl<<<R, 256, 0, stream>>>(ghb, idr + r0, idl + r0, addb);
    f_fc<<<R, 256, 0, stream>>>(gxb, ghb, c0 + r0 * HID, idd + r0, idr + r0, idl + r0, fcb);
    final_k<<<R, 256, 0, stream>>>(gxb, addb, fcb, h0, c0, idd + r0, sel, mcnt, hout, cout, (int)r0);
  }
}

// Round 3
// 561.681 us; speedup vs baseline: 2.0355x; 2.0355x over previous
//
#include <hip/hip_runtime.h>

// NaryTreeLSTMCell: B=32, L=512, E=H=1024.  Outputs h_out, c_out (f32, 2x16384x1024).
//
// Math:
//   gx = x @ [W_ioux | W_fx]                      -> [16384][4096] (cols: i,o,u,fx)
//   gh = h0 @ [Wiouh0[:, :H] | Wiouh1[:, :H] | Wfh0+Wfh1 | Wfh2+Wfh3] + bias
//                                                 -> [16384][4096] (cols: hr_i,hl_i,fr,fl)
//   add[j]  = sum_{l:idr[l]=j} gh[l,0:H] + sum_{l:idl[l]=j} gh[l,H:2H]      (per batch)
//   fc[j]   = sum_{l:idd[l]=j} sigmoid(gx[j,3H:]+gh[idr[l],2H:3H]+gh[idl[l],3H:])*c0[l]
//   i,o,u = sig(gx_i+add), sig(gx_o), tanh(gx_u);  c_new = i*u + fc;  h_new = o*tanh(c_new)
//   masked_scatter == compaction: k-th selected row (idd!=0 flat order) <- h_new/c_new row k.
//
// Round-2 counters showed atomic scatters at 16% HBM with 4x write amplification
// (436us scatter_hrhl). This version replaces ALL atomics with per-batch CSR
// contributor lists (deterministic, sorted) + one fused gather/epilogue kernel.

#define ROWS 16384   // B*L
#define HID  1024
#define KDIM 1024
#define NCOLS 4096
#define TM 128
#define TN 128
#define TK 32

typedef __attribute__((ext_vector_type(4))) int            i32x4;
typedef __attribute__((ext_vector_type(4))) float          f32x4;
typedef __attribute__((ext_vector_type(4))) unsigned short u16x4;

__device__ __forceinline__ unsigned short f2bf(float f) {
  unsigned u = __float_as_uint(f);
  unsigned r = 0x7FFFu + ((u >> 16) & 1u);
  return (unsigned short)((u + r) >> 16);
}
__device__ __forceinline__ float bf2f(unsigned short v) {
  return __uint_as_float(((unsigned)v) << 16);
}
__device__ __forceinline__ float sigmoidf_(float x) {
  return 1.0f / (1.0f + __expf(-x));
}
__device__ __forceinline__ void gload16(const void* g, void* l) {
  __builtin_amdgcn_global_load_lds(
      (const __attribute__((address_space(1))) void*)g,
      (__attribute__((address_space(3))) void*)l, 16, 0, 0);
}
// A and B fragments use the SAME (lane,elem)->k storage mapping, so any HW
// k-permutation cancels in the dot product (m97-verified structure).
__device__ __forceinline__ void mfma_bf16(f32x4& acc, i32x4 a, i32x4 b) {
  asm volatile("v_mfma_f32_16x16x32_bf16 %0, %1, %2, %0"
               : "+v"(acc) : "v"(a), "v"(b));
}

// ---- weight packing: transposed bf16 panels [N=4096][K=1024] ----

__global__ void pack_wx(const float* __restrict__ Wioux, const float* __restrict__ Wfx,
                        unsigned short* __restrict__ Wxt) {
  __shared__ float t[32][33];
  const int n0 = blockIdx.x * 32, k0 = blockIdx.y * 32;
  const int tx = threadIdx.x, ty = threadIdx.y;
  const int n = n0 + tx, k = k0 + ty;
  float v = (n < 3072) ? Wioux[(size_t)k * 3072 + n]
                       : Wfx[(size_t)k * 1024 + (n - 3072)];
  t[ty][tx] = v;
  __syncthreads();
  Wxt[(size_t)(n0 + ty) * KDIM + (k0 + tx)] = f2bf(t[tx][ty]);
}

__global__ void pack_wh(const float* __restrict__ Wiouh, const float* __restrict__ Wfh,
                        unsigned short* __restrict__ Wht) {
  __shared__ float t[32][33];
  const int n0 = blockIdx.x * 32, k0 = blockIdx.y * 32;
  const int tx = threadIdx.x, ty = threadIdx.y;
  const int n = n0 + tx, k = k0 + ty;
  float v;
  if (n < 1024)      v = Wiouh[(size_t)k * 3072 + n];
  else if (n < 2048) v = Wiouh[3145728u + (size_t)k * 3072 + (n - 1024)];
  else if (n < 3072) { const int c = n - 2048;
    v = Wfh[(size_t)k * 1024 + c] + Wfh[1048576u + (size_t)k * 1024 + c]; }
  else { const int c = n - 3072;
    v = Wfh[2097152u + (size_t)k * 1024 + c] + Wfh[3145728u + (size_t)k * 1024 + c]; }
  t[ty][tx] = v;
  __syncthreads();
  Wht[(size_t)(n0 + ty) * KDIM + (k0 + tx)] = f2bf(t[tx][ty]);
}

__global__ void pack_bias(const float* __restrict__ b_iouh, const float* __restrict__ b_fh,
                          float* __restrict__ bh) {
  const int n = blockIdx.x * 1024 + threadIdx.x;
  float v;
  if (n < 1024)      v = b_iouh[n];
  else if (n < 2048) v = b_iouh[3072 + (n - 1024)];
  else if (n < 3072) { const int c = n - 2048; v = b_fh[c] + b_fh[1024 + c]; }
  else { const int c = n - 3072; v = b_fh[2048 + c] + b_fh[3072 + c]; }
  bh[n] = v;
}

// chunked: converts R*1024 elems of x and h0 (pointers pre-offset to chunk start)
__global__ void convert_bf16(const float* __restrict__ x, const float* __restrict__ h0,
                             unsigned short* __restrict__ xb, unsigned short* __restrict__ hb) {
  const size_t i = ((size_t)blockIdx.x * 256 + threadIdx.x) * 4;
  const float4 a = *(const float4*)&x[i];
  const float4 b = *(const float4*)&h0[i];
  u16x4 av = { f2bf(a.x), f2bf(a.y), f2bf(a.z), f2bf(a.w) };
  u16x4 bv = { f2bf(b.x), f2bf(b.y), f2bf(b.z), f2bf(b.w) };
  *(u16x4*)&xb[i] = av;
  *(u16x4*)&hb[i] = bv;
}

// ---- GEMM (m97 structure): 128x128 tile, BK=32, 4 waves, global_load_lds w16.
__global__ __launch_bounds__(256)
void gemm_both(const unsigned short* __restrict__ xb, const unsigned short* __restrict__ hb,
               const unsigned short* __restrict__ Wxt, const unsigned short* __restrict__ Wht,
               unsigned short* __restrict__ gxb, unsigned short* __restrict__ ghb,
               const float* __restrict__ bhv) {
  __shared__ __align__(16) unsigned short As[TM * TK];
  __shared__ __align__(16) unsigned short Bs[TN * TK];

  const unsigned short* A;
  const unsigned short* Bt;
  unsigned short* Cp;
  const float* bias;
  if (blockIdx.z == 0) { A = xb; Bt = Wxt; Cp = gxb; bias = nullptr; }
  else                 { A = hb; Bt = Wht; Cp = ghb; bias = bhv; }

  const int tid = threadIdx.x;
  const int w = tid >> 6, lane = tid & 63;
  const int bm = blockIdx.y * TM, bn = blockIdx.x * TN;
  const int wm = (w & 1) * 64, wn = (w >> 1) * 64;
  const int m0 = lane & 15, kg = lane >> 4;

  const int srow = w * 16 + (lane >> 2);
  const int sseg = (lane & 3) * 8;
  const unsigned short* ga0 = A  + (size_t)(bm + srow) * KDIM + sseg;
  const unsigned short* ga1 = ga0 + (size_t)64 * KDIM;
  const unsigned short* gb0 = Bt + (size_t)(bn + srow) * KDIM + sseg;
  const unsigned short* gb1 = gb0 + (size_t)64 * KDIM;
  unsigned short* la0 = &As[(w * 16) * TK];
  unsigned short* la1 = &As[(64 + w * 16) * TK];
  unsigned short* lb0 = &Bs[(w * 16) * TK];
  unsigned short* lb1 = &Bs[(64 + w * 16) * TK];

  const int aoff = (wm + m0) * TK + kg * 8;
  const int boff = (wn + m0) * TK + kg * 8;

  f32x4 acc[4][4] = {};

  for (int k0 = 0; k0 < KDIM; k0 += TK) {
    gload16(ga0 + k0, la0);
    gload16(ga1 + k0, la1);
    gload16(gb0 + k0, lb0);
    gload16(gb1 + k0, lb1);
    __syncthreads();
    i32x4 af[4], bf[4];
#pragma unroll
    for (int i = 0; i < 4; ++i) af[i] = *(const i32x4*)&As[aoff + i * 16 * TK];
#pragma unroll
    for (int j = 0; j < 4; ++j) bf[j] = *(const i32x4*)&Bs[boff + j * 16 * TK];
#pragma unroll
    for (int i = 0; i < 4; ++i)
#pragma unroll
      for (int j = 0; j < 4; ++j)
        mfma_bf16(acc[i][j], af[i], bf[j]);
    __syncthreads();
  }

  const int rg = (lane >> 4) * 4;
#pragma unroll
  for (int i = 0; i < 4; ++i) {
#pragma unroll
    for (int j = 0; j < 4; ++j) {
      const int col = bn + wn + j * 16 + m0;
      const float bv = bias ? bias[col] : 0.0f;
      const int row = bm + wm + i * 16 + rg;
#pragma unroll
      for (int r = 0; r < 4; ++r)
        Cp[(size_t)(row + r) * NCOLS + col] = f2bf(acc[i][j][r] + bv);
    }
  }
}

// ---- global mask compaction scan: sel[k] = flat row index of k-th selected row ----
__global__ void scan_mask(const int* __restrict__ idd, int* __restrict__ sel,
                          int* __restrict__ mcount) {
  __shared__ int ps[1024];
  const int t = threadIdx.x;
  int loc[16];
  int cnt = 0;
#pragma unroll
  for (int i = 0; i < 16; ++i) {
    const int v = (idd[t * 16 + i] != 0) ? 1 : 0;
    loc[i] = v; cnt += v;
  }
  ps[t] = cnt;
  __syncthreads();
  for (int off = 1; off < 1024; off <<= 1) {
    const int add = (t >= off) ? ps[t - off] : 0;
    __syncthreads();
    ps[t] += add;
    __syncthreads();
  }
  int rank = (t == 0) ? 0 : ps[t - 1];
#pragma unroll
  for (int i = 0; i < 16; ++i)
    if (loc[i]) sel[rank++] = t * 16 + i;
  if (t == 1023) *mcount = ps[1023];
}

// ---- per-batch CSR build: for each idx array, ofs[b][j]..ofs[b][j+1] spans
// lst entries = SORTED local source rows l with idx[l]==j. Deterministic. ----
__global__ void build_csr(const int* __restrict__ idd, const int* __restrict__ idr,
                          const int* __restrict__ idl,
                          int* __restrict__ ofsD, int* __restrict__ ofsR, int* __restrict__ ofsL,
                          int* __restrict__ lstD, int* __restrict__ lstR, int* __restrict__ lstL) {
  __shared__ int sidx[512];
  __shared__ int scan[512];
  const int b = blockIdx.x, t = threadIdx.x;
  const int gb = b << 9;
  const int* const srcs[3] = { idd, idr, idl };
  int* const ofss[3] = { ofsD, ofsR, ofsL };
  int* const lsts[3] = { lstD, lstR, lstL };
  for (int a = 0; a < 3; ++a) {
    sidx[t] = srcs[a][gb + t];
    scan[t] = 0;
    __syncthreads();
    atomicAdd(&scan[sidx[t]], 1);          // counts per target slot
    __syncthreads();
    int v = scan[t];
    // inclusive scan (Hillis-Steele)
    for (int off = 1; off < 512; off <<= 1) {
      const int add = (t >= off) ? scan[t - off] : 0;
      __syncthreads();
      scan[t] += add;
      __syncthreads();
    }
    const int start = scan[t] - v;         // exclusive offset for slot t
    ofss[a][b * 513 + t] = start;
    if (t == 511) ofss[a][b * 513 + 512] = scan[511];
    // stable fill: thread t owns output slot t, appends matching sources in order
    int pos = start;
    for (int l = 0; l < 512; ++l)
      if (sidx[l] == t) lsts[a][gb + (pos++)] = l;
    __syncthreads();
  }
}

// ---- fused epilogue: gather-add + f-gate + activations + compaction write ----
// One block per chunk-local row r (global row g=r0+r); 256 threads x 4 cols.
__global__ __launch_bounds__(256)
void fused_final(const unsigned short* __restrict__ gxb, const unsigned short* __restrict__ ghb,
                 const float* __restrict__ h0, const float* __restrict__ c0,
                 const int* __restrict__ idd, const int* __restrict__ idr,
                 const int* __restrict__ idl,
                 const int* __restrict__ ofsR, const int* __restrict__ lstR,
                 const int* __restrict__ ofsL, const int* __restrict__ lstL,
                 const int* __restrict__ ofsD, const int* __restrict__ lstD,
                 const int* __restrict__ sel, const int* __restrict__ mcount,
                 float* __restrict__ hout, float* __restrict__ cout, int r0) {
  const int r = blockIdx.x;              // chunk-local row
  const int g = r0 + r;                  // global flat row
  const int j = g & 511;                 // slot within batch
  const int bb = g >> 9;                 // global batch
  const int lbase = (r >> 9) << 9;       // chunk-local batch base row
  const int ob = bb * 513;
  const int lb = bb << 9;
  const int c = threadIdx.x << 2;

  // i-gate additions: gather gh[l, 0:1024] over listR, gh[l, 1024:2048] over listL
  float a0 = 0.f, a1 = 0.f, a2 = 0.f, a3 = 0.f;
  for (int q = ofsR[ob + j], e = ofsR[ob + j + 1]; q < e; ++q) {
    const int l = lstR[lb + q];
    const u16x4 v = *(const u16x4*)&ghb[(size_t)(lbase + l) * NCOLS + c];
    a0 += bf2f(v[0]); a1 += bf2f(v[1]); a2 += bf2f(v[2]); a3 += bf2f(v[3]);
  }
  for (int q = ofsL[ob + j], e = ofsL[ob + j + 1]; q < e; ++q) {
    const int l = lstL[lb + q];
    const u16x4 v = *(const u16x4*)&ghb[(size_t)(lbase + l) * NCOLS + 1024 + c];
    a0 += bf2f(v[0]); a1 += bf2f(v[1]); a2 += bf2f(v[2]); a3 += bf2f(v[3]);
  }

  // fc: for contributors l with idd[l]==j, f uses fx row j (this row's gx)
  const u16x4 fx4 = *(const u16x4*)&gxb[(size_t)r * NCOLS + 3072 + c];
  const float fx0 = bf2f(fx4[0]), fx1 = bf2f(fx4[1]), fx2 = bf2f(fx4[2]), fx3 = bf2f(fx4[3]);
  float fc0 = 0.f, fc1 = 0.f, fc2 = 0.f, fc3 = 0.f;
  for (int q = ofsD[ob + j], e = ofsD[ob + j + 1]; q < e; ++q) {
    const int l = lstD[lb + q];
    const int jr = idr[lb + l], jl = idl[lb + l];
    const u16x4 rv = *(const u16x4*)&ghb[(size_t)(lbase + jr) * NCOLS + 2048 + c];
    const u16x4 lv = *(const u16x4*)&ghb[(size_t)(lbase + jl) * NCOLS + 3072 + c];
    const float4 cc = *(const float4*)&c0[(size_t)(lb + l) * HID + c];
    fc0 += sigmoidf_(fx0 + bf2f(rv[0]) + bf2f(lv[0])) * cc.x;
    fc1 += sigmoidf_(fx1 + bf2f(rv[1]) + bf2f(lv[1])) * cc.y;
    fc2 += sigmoidf_(fx2 + bf2f(rv[2]) + bf2f(lv[2])) * cc.z;
    fc3 += sigmoidf_(fx3 + bf2f(rv[3]) + bf2f(lv[3])) * cc.w;
  }

  // gates + state update
  const u16x4 vi = *(const u16x4*)&gxb[(size_t)r * NCOLS + c];
  const u16x4 vo = *(const u16x4*)&gxb[(size_t)r * NCOLS + 1024 + c];
  const u16x4 vu = *(const u16x4*)&gxb[(size_t)r * NCOLS + 2048 + c];
  float4 hn, cn;
  {
    const float ig = sigmoidf_(bf2f(vi[0]) + a0), og = sigmoidf_(bf2f(vo[0]));
    cn.x = ig * tanhf(bf2f(vu[0])) + fc0; hn.x = og * tanhf(cn.x);
  }
  {
    const float ig = sigmoidf_(bf2f(vi[1]) + a1), og = sigmoidf_(bf2f(vo[1]));
    cn.y = ig * tanhf(bf2f(vu[1])) + fc1; hn.y = og * tanhf(cn.y);
  }
  {
    const float ig = sigmoidf_(bf2f(vi[2]) + a2), og = sigmoidf_(bf2f(vo[2]));
    cn.z = ig * tanhf(bf2f(vu[2])) + fc2; hn.z = og * tanhf(cn.z);
  }
  {
    const float ig = sigmoidf_(bf2f(vi[3]) + a3), og = sigmoidf_(bf2f(vo[3]));
    cn.w = ig * tanhf(bf2f(vu[3])) + fc3; hn.w = og * tanhf(cn.w);
  }

  if (idd[g] == 0) {                     // unselected output rows keep h0/c0
    *(float4*)&hout[(size_t)g * HID + c] = *(const float4*)&h0[(size_t)g * HID + c];
    *(float4*)&cout[(size_t)g * HID + c] = *(const float4*)&c0[(size_t)g * HID + c];
  }
  const int m = *mcount;
  if (g < m) {                           // h_new/c_new flat row g -> output row sel[g]
    const int o = sel[g];
    *(float4*)&hout[(size_t)o * HID + c] = hn;
    *(float4*)&cout[(size_t)o * HID + c] = cn;
  }
}

extern "C" void kernel_launch(void* const* d_in, const int* in_sizes, int n_in,
                              void* d_out, int out_size, void* d_ws, size_t ws_size,
                              hipStream_t stream) {
  const float* x      = (const float*)d_in[0];
  const float* h0     = (const float*)d_in[1];
  const float* c0     = (const float*)d_in[2];
  const float* W_ioux = (const float*)d_in[3];
  const float* W_iouh = (const float*)d_in[4];
  const float* b_iouh = (const float*)d_in[5];
  const float* W_fx   = (const float*)d_in[6];
  const float* W_fh   = (const float*)d_in[7];
  const float* b_fh   = (const float*)d_in[8];
  const int* idd      = (const int*)d_in[9];
  const int* idr      = (const int*)d_in[10];
  const int* idl      = (const int*)d_in[11];
  float* hout = (float*)d_out;
  float* cout = hout + (size_t)ROWS * HID;

  // fixed region (~17.3 MB)
  char* ws = (char*)d_ws;
  unsigned short* Wxt  = (unsigned short*)(ws);              // 8 MiB
  unsigned short* Wht  = (unsigned short*)(ws + 8388608u);   // 8 MiB
  float*          bh   = (float*)(ws + 16777216u);           // 16 KiB
  int*            sel  = (int*)(ws + 16793600u);             // 64 KiB
  int*            mcnt = (int*)(ws + 16859136u);             // 256 B
  int*            ofsD = (int*)(ws + 16859392u);             // 65,792 each
  int*            ofsR = (int*)(ws + 16925184u);
  int*            ofsL = (int*)(ws + 16990976u);
  int*            lstD = (int*)(ws + 17056768u);             // 64 KiB each
  int*            lstR = (int*)(ws + 17122304u);
  int*            lstL = (int*)(ws + 17187840u);
  const size_t    base = 17253376u;

  // chunk size: largest power-of-two divisor of 32 fitting ws (10 MiB per batch)
  int C = 32;
  while (C > 1 && base + 10485760ull * (size_t)C > ws_size) C >>= 1;
  const int R = 512 * C;

  char* p = ws + base;
  unsigned short* xb  = (unsigned short*)p;  p += 1048576ull * C;
  unsigned short* hb  = (unsigned short*)p;  p += 1048576ull * C;
  unsigned short* gxb = (unsigned short*)p;  p += 4194304ull * C;
  unsigned short* ghb = (unsigned short*)p;

  pack_wx<<<dim3(128, 32), dim3(32, 32), 0, stream>>>(W_ioux, W_fx, Wxt);
  pack_wh<<<dim3(128, 32), dim3(32, 32), 0, stream>>>(W_iouh, W_fh, Wht);
  pack_bias<<<4, 1024, 0, stream>>>(b_iouh, b_fh, bh);
  scan_mask<<<1, 1024, 0, stream>>>(idd, sel, mcnt);
  build_csr<<<32, 512, 0, stream>>>(idd, idr, idl, ofsD, ofsR, ofsL, lstD, lstR, lstL);

  for (int b0 = 0; b0 < 32; b0 += C) {
    const size_t r0 = (size_t)b0 * 512;
    convert_bf16<<<R, 256, 0, stream>>>(x + r0 * HID, h0 + r0 * HID, xb, hb);
    gemm_both<<<dim3(NCOLS / TN, R / TM, 2), 256, 0, stream>>>(xb, hb, Wxt, Wht, gxb, ghb, bh);
    fused_final<<<R, 256, 0, stream>>>(gxb, ghb, h0, c0, idd, idr, idl,
                                       ofsR, lstR, ofsL, lstL, ofsD, lstD,
                                       sel, mcnt, hout, cout, (int)r0);
  }
}

// Round 4
// 552.803 us; speedup vs baseline: 2.0682x; 1.0161x over previous
//
#include <hip/hip_runtime.h>

// NaryTreeLSTMCell: B=32, L=512, E=H=1024.  Outputs h_out, c_out (f32, 2x16384x1024).
//
//   gx = x @ [W_ioux | W_fx]                      -> [16384][4096] (cols: i,o,u,fx)
//   gh = h0 @ [Wiouh0[:,:H] | Wiouh1[:,:H] | Wfh0+Wfh1 | Wfh2+Wfh3] + bias
//   add[j] = sum_{idr=j} gh[l,0:H] + sum_{idl=j} gh[l,H:2H]          (per batch)
//   fc[j]  = sum_{idd=j} sigmoid(gx[j,3H:]+gh[idr[l],2H:3H]+gh[idl[l],3H:])*c0[l]
//   i,o,u gates -> c_new, h_new; masked_scatter == compaction via sel[].
//
// Round-3: gemm_both (m97 128^2 structure) = 347us, MfmaUtil 36%, 3.4e7 LDS bank
// conflicts -> at the documented ~900TF structural ceiling. This round ports the
// 256^2 8-phase schedule (T2 swizzle + T3/T4 counted vmcnt + T5 setprio):
//   BM=BN=256, BK=64, 8 waves, 128KiB LDS double-buffer.
//   Per K-tile: 4 phases, each {12x ds_read_b128 ; 2x global_load_lds ; [vmcnt(N)] ;
//   barrier ; setprio(1) ; 16 MFMA ; setprio(0) ; barrier}.
//   Stage order A0,B0,B1,A1; waits: vmcnt(4) @p1-end, vmcnt(2) @p3-end (never 0).
//   T2: LDS seg XOR row&7 via pre-swizzled global source + swizzled ds_read.

#define ROWS 16384
#define HID  1024
#define KDIM 1024
#define NCOLS 4096
#define BM 256
#define BN 256
#define BK 64

typedef __attribute__((ext_vector_type(4))) int            i32x4;
typedef __attribute__((ext_vector_type(4))) float          f32x4;
typedef __attribute__((ext_vector_type(4))) unsigned short u16x4;

__device__ __forceinline__ unsigned short f2bf(float f) {
  unsigned u = __float_as_uint(f);
  unsigned r = 0x7FFFu + ((u >> 16) & 1u);
  return (unsigned short)((u + r) >> 16);
}
__device__ __forceinline__ float bf2f(unsigned short v) {
  return __uint_as_float(((unsigned)v) << 16);
}
__device__ __forceinline__ float sigmoidf_(float x) {
  return 1.0f / (1.0f + __expf(-x));
}
__device__ __forceinline__ void gload16(const void* g, void* l) {
  __builtin_amdgcn_global_load_lds(
      (const __attribute__((address_space(1))) void*)g,
      (__attribute__((address_space(3))) void*)l, 16, 0, 0);
}
__device__ __forceinline__ void mfma_bf16(f32x4& acc, i32x4 a, i32x4 b) {
  asm volatile("v_mfma_f32_16x16x32_bf16 %0, %1, %2, %0"
               : "+v"(acc) : "v"(a), "v"(b));
}

// ---- weight packing: transposed bf16 panels [N=4096][K=1024] ----

__global__ void pack_wx(const float* __restrict__ Wioux, const float* __restrict__ Wfx,
                        unsigned short* __restrict__ Wxt) {
  __shared__ float t[32][33];
  const int n0 = blockIdx.x * 32, k0 = blockIdx.y * 32;
  const int tx = threadIdx.x, ty = threadIdx.y;
  const int n = n0 + tx, k = k0 + ty;
  float v = (n < 3072) ? Wioux[(size_t)k * 3072 + n]
                       : Wfx[(size_t)k * 1024 + (n - 3072)];
  t[ty][tx] = v;
  __syncthreads();
  Wxt[(size_t)(n0 + ty) * KDIM + (k0 + tx)] = f2bf(t[tx][ty]);
}

__global__ void pack_wh(const float* __restrict__ Wiouh, const float* __restrict__ Wfh,
                        unsigned short* __restrict__ Wht) {
  __shared__ float t[32][33];
  const int n0 = blockIdx.x * 32, k0 = blockIdx.y * 32;
  const int tx = threadIdx.x, ty = threadIdx.y;
  const int n = n0 + tx, k = k0 + ty;
  float v;
  if (n < 1024)      v = Wiouh[(size_t)k * 3072 + n];
  else if (n < 2048) v = Wiouh[3145728u + (size_t)k * 3072 + (n - 1024)];
  else if (n < 3072) { const int c = n - 2048;
    v = Wfh[(size_t)k * 1024 + c] + Wfh[1048576u + (size_t)k * 1024 + c]; }
  else { const int c = n - 3072;
    v = Wfh[2097152u + (size_t)k * 1024 + c] + Wfh[3145728u + (size_t)k * 1024 + c]; }
  t[ty][tx] = v;
  __syncthreads();
  Wht[(size_t)(n0 + ty) * KDIM + (k0 + tx)] = f2bf(t[tx][ty]);
}

__global__ void pack_bias(const float* __restrict__ b_iouh, const float* __restrict__ b_fh,
                          float* __restrict__ bh) {
  const int n = blockIdx.x * 1024 + threadIdx.x;
  float v;
  if (n < 1024)      v = b_iouh[n];
  else if (n < 2048) v = b_iouh[3072 + (n - 1024)];
  else if (n < 3072) { const int c = n - 2048; v = b_fh[c] + b_fh[1024 + c]; }
  else { const int c = n - 3072; v = b_fh[2048 + c] + b_fh[3072 + c]; }
  bh[n] = v;
}

__global__ void convert_bf16(const float* __restrict__ x, const float* __restrict__ h0,
                             unsigned short* __restrict__ xb, unsigned short* __restrict__ hb) {
  const size_t i = ((size_t)blockIdx.x * 256 + threadIdx.x) * 4;
  const float4 a = *(const float4*)&x[i];
  const float4 b = *(const float4*)&h0[i];
  u16x4 av = { f2bf(a.x), f2bf(a.y), f2bf(a.z), f2bf(a.w) };
  u16x4 bv = { f2bf(b.x), f2bf(b.y), f2bf(b.z), f2bf(b.w) };
  *(u16x4*)&xb[i] = av;
  *(u16x4*)&hb[i] = bv;
}

// ---- 256x256 8-phase GEMM ----
// Stage one 8-row slice per wave (one gload/wave): lane -> (row=rowbase+(lane>>3),
// seg=lane&7). Global source seg pre-swizzled by ^(row&7); LDS stays linear.
__device__ __forceinline__ void stage8(const unsigned short* __restrict__ gp,
                                       unsigned short* __restrict__ lp,
                                       int rowbase, int gbase, int k0, int lane) {
  const int lrow = rowbase + (lane >> 3);
  const int sseg = (lane & 7) ^ ((lane >> 3) & 7);   // rowbase is a multiple of 8
  gload16(gp + (size_t)(gbase + lrow) * KDIM + k0 + sseg * 8,
          lp + ((size_t)rowbase << 6));
}

#define PHASE(qm, qn, STAGES, VM)                                            \
  {                                                                          \
    i32x4 af[4][2], bfr[2][2];                                               \
    const unsigned short* Ab = &S[b][0][0][0];                               \
    const unsigned short* Bb = &S[b][1][0][0];                               \
    _Pragma("unroll")                                                        \
    for (int i = 0; i < 4; ++i) {                                            \
      const int row = wr * 128 + (qm) * 64 + i * 16 + m0;                    \
      _Pragma("unroll")                                                      \
      for (int s = 0; s < 2; ++s)                                            \
        af[i][s] = *(const i32x4*)(Ab + row * 64 + (((kg + s * 4) ^ sw8) << 3)); \
    }                                                                        \
    _Pragma("unroll")                                                        \
    for (int j = 0; j < 2; ++j) {                                            \
      const int col = wc * 64 + (qn) * 32 + j * 16 + m0;                     \
      _Pragma("unroll")                                                      \
      for (int s = 0; s < 2; ++s)                                            \
        bfr[j][s] = *(const i32x4*)(Bb + col * 64 + (((kg + s * 4) ^ sw8) << 3)); \
    }                                                                        \
    STAGES;                                                                  \
    VM;                                                                      \
    __builtin_amdgcn_s_barrier();                                            \
    __builtin_amdgcn_s_setprio(1);                                           \
    _Pragma("unroll")                                                        \
    for (int i = 0; i < 4; ++i)                                              \
      _Pragma("unroll")                                                      \
      for (int j = 0; j < 2; ++j) {                                          \
        mfma_bf16(acc[(qm) * 4 + i][(qn) * 2 + j], af[i][0], bfr[j][0]);     \
        mfma_bf16(acc[(qm) * 4 + i][(qn) * 2 + j], af[i][1], bfr[j][1]);     \
      }                                                                      \
    __builtin_amdgcn_s_setprio(0);                                           \
    __builtin_amdgcn_s_barrier();                                            \
  }

__global__ __launch_bounds__(512, 2)
void gemm8(const unsigned short* __restrict__ xb, const unsigned short* __restrict__ hb,
           const unsigned short* __restrict__ Wxt, const unsigned short* __restrict__ Wht,
           unsigned short* __restrict__ gxb, unsigned short* __restrict__ ghb,
           const float* __restrict__ bhv) {
  __shared__ __align__(16) unsigned short S[2][2][256][64];  // [buf][A|B][row][64]

  const unsigned short* A;
  const unsigned short* Bt;
  unsigned short* Cp;
  const float* bias;
  if (blockIdx.z == 0) { A = xb; Bt = Wxt; Cp = gxb; bias = nullptr; }
  else                 { A = hb; Bt = Wht; Cp = ghb; bias = bhv; }

  const int tid = threadIdx.x, w = tid >> 6, lane = tid & 63;
  const int wr = w >> 2, wc = w & 3;
  const int bm = blockIdx.y * BM, bn = blockIdx.x * BN;
  const int m0 = lane & 15, kg = lane >> 4, sw8 = m0 & 7;
  const int bb0 = (w >> 2) * 64 + (w & 3) * 8;   // B-quarter wave row base

  f32x4 acc[8][4] = {};

  // prologue: stage tile 0 into buf 0, drain once
  stage8(A,  &S[0][0][0][0], w * 8,        bm, 0, lane);
  stage8(A,  &S[0][0][0][0], 128 + w * 8,  bm, 0, lane);
  stage8(A,  &S[0][0][0][0], 64 + w * 8,   bm, 0, lane);
  stage8(A,  &S[0][0][0][0], 192 + w * 8,  bm, 0, lane);
  stage8(Bt, &S[0][1][0][0], bb0,          bn, 0, lane);
  stage8(Bt, &S[0][1][0][0], bb0 + 128,    bn, 0, lane);
  stage8(Bt, &S[0][1][0][0], bb0 + 32,     bn, 0, lane);
  stage8(Bt, &S[0][1][0][0], bb0 + 160,    bn, 0, lane);
  asm volatile("s_waitcnt vmcnt(0)");
  __builtin_amdgcn_s_barrier();

  for (int t = 0; t < 16; ++t) {
    const int b = t & 1, nb = b ^ 1;
    const int k1 = (t + 1) << 6;
    const bool st = (t < 15);
    unsigned short* An = &S[nb][0][0][0];
    unsigned short* Bn = &S[nb][1][0][0];

    // p0: compute quad(0,0); stage A-quarter0 of tile t+1
    PHASE(0, 0,
      { if (st) { stage8(A, An, w * 8, bm, k1, lane);
                  stage8(A, An, 128 + w * 8, bm, k1, lane); } },
      {});
    // p1: compute quad(0,1); stage B-quarter0; retire A-quarter1 of tile t
    PHASE(0, 1,
      { if (st) { stage8(Bt, Bn, bb0, bn, k1, lane);
                  stage8(Bt, Bn, bb0 + 128, bn, k1, lane); } },
      { if (st) asm volatile("s_waitcnt vmcnt(4)");
        else    asm volatile("s_waitcnt vmcnt(0)"); });
    // p2: compute quad(1,0); stage B-quarter1
    PHASE(1, 0,
      { if (st) { stage8(Bt, Bn, bb0 + 32, bn, k1, lane);
                  stage8(Bt, Bn, bb0 + 160, bn, k1, lane); } },
      {});
    // p3: compute quad(1,1); stage A-quarter1; retire A0/B0/B1 of tile t+1
    PHASE(1, 1,
      { if (st) { stage8(A, An, 64 + w * 8, bm, k1, lane);
                  stage8(A, An, 192 + w * 8, bm, k1, lane); } },
      { asm volatile("s_waitcnt vmcnt(2)"); });
  }

  // C/D layout (m89/m91): col = lane&15, row = 4*(lane>>4)+reg
  const int rg = kg * 4;
#pragma unroll
  for (int mi = 0; mi < 8; ++mi) {
#pragma unroll
    for (int nj = 0; nj < 4; ++nj) {
      const int col = bn + wc * 64 + nj * 16 + m0;
      const float bv = bias ? bias[col] : 0.0f;
      const int row = bm + wr * 128 + mi * 16 + rg;
#pragma unroll
      for (int r = 0; r < 4; ++r)
        Cp[(size_t)(row + r) * NCOLS + col] = f2bf(acc[mi][nj][r] + bv);
    }
  }
}

// ---- global mask compaction scan ----
__global__ void scan_mask(const int* __restrict__ idd, int* __restrict__ sel,
                          int* __restrict__ mcount) {
  __shared__ int ps[1024];
  const int t = threadIdx.x;
  int loc[16];
  int cnt = 0;
#pragma unroll
  for (int i = 0; i < 16; ++i) {
    const int v = (idd[t * 16 + i] != 0) ? 1 : 0;
    loc[i] = v; cnt += v;
  }
  ps[t] = cnt;
  __syncthreads();
  for (int off = 1; off < 1024; off <<= 1) {
    const int add = (t >= off) ? ps[t - off] : 0;
    __syncthreads();
    ps[t] += add;
    __syncthreads();
  }
  int rank = (t == 0) ? 0 : ps[t - 1];
#pragma unroll
  for (int i = 0; i < 16; ++i)
    if (loc[i]) sel[rank++] = t * 16 + i;
  if (t == 1023) *mcount = ps[1023];
}

// ---- per-batch CSR (deterministic, sorted contributor lists) ----
__global__ void build_csr(const int* __restrict__ idd, const int* __restrict__ idr,
                          const int* __restrict__ idl,
                          int* __restrict__ ofsD, int* __restrict__ ofsR, int* __restrict__ ofsL,
                          int* __restrict__ lstD, int* __restrict__ lstR, int* __restrict__ lstL) {
  __shared__ int sidx[512];
  __shared__ int scan[512];
  const int b = blockIdx.x, t = threadIdx.x;
  const int gb = b << 9;
  const int* const srcs[3] = { idd, idr, idl };
  int* const ofss[3] = { ofsD, ofsR, ofsL };
  int* const lsts[3] = { lstD, lstR, lstL };
  for (int a = 0; a < 3; ++a) {
    sidx[t] = srcs[a][gb + t];
    scan[t] = 0;
    __syncthreads();
    atomicAdd(&scan[sidx[t]], 1);
    __syncthreads();
    int v = scan[t];
    for (int off = 1; off < 512; off <<= 1) {
      const int add = (t >= off) ? scan[t - off] : 0;
      __syncthreads();
      scan[t] += add;
      __syncthreads();
    }
    const int start = scan[t] - v;
    ofss[a][b * 513 + t] = start;
    if (t == 511) ofss[a][b * 513 + 512] = scan[511];
    int pos = start;
    for (int l = 0; l < 512; ++l)
      if (sidx[l] == t) lsts[a][gb + (pos++)] = l;
    __syncthreads();
  }
}

// ---- fused epilogue: gather-add + f-gate + activations + compaction write ----
__global__ __launch_bounds__(256)
void fused_final(const unsigned short* __restrict__ gxb, const unsigned short* __restrict__ ghb,
                 const float* __restrict__ h0, const float* __restrict__ c0,
                 const int* __restrict__ idd, const int* __restrict__ idr,
                 const int* __restrict__ idl,
                 const int* __restrict__ ofsR, const int* __restrict__ lstR,
                 const int* __restrict__ ofsL, const int* __restrict__ lstL,
                 const int* __restrict__ ofsD, const int* __restrict__ lstD,
                 const int* __restrict__ sel, const int* __restrict__ mcount,
                 float* __restrict__ hout, float* __restrict__ cout, int r0) {
  const int r = blockIdx.x;
  const int g = r0 + r;
  const int j = g & 511;
  const int bb = g >> 9;
  const int lbase = (r >> 9) << 9;
  const int ob = bb * 513;
  const int lb = bb << 9;
  const int c = threadIdx.x << 2;

  float a0 = 0.f, a1 = 0.f, a2 = 0.f, a3 = 0.f;
  for (int q = ofsR[ob + j], e = ofsR[ob + j + 1]; q < e; ++q) {
    const int l = lstR[lb + q];
    const u16x4 v = *(const u16x4*)&ghb[(size_t)(lbase + l) * NCOLS + c];
    a0 += bf2f(v[0]); a1 += bf2f(v[1]); a2 += bf2f(v[2]); a3 += bf2f(v[3]);
  }
  for (int q = ofsL[ob + j], e = ofsL[ob + j + 1]; q < e; ++q) {
    const int l = lstL[lb + q];
    const u16x4 v = *(const u16x4*)&ghb[(size_t)(lbase + l) * NCOLS + 1024 + c];
    a0 += bf2f(v[0]); a1 += bf2f(v[1]); a2 += bf2f(v[2]); a3 += bf2f(v[3]);
  }

  const u16x4 fx4 = *(const u16x4*)&gxb[(size_t)r * NCOLS + 3072 + c];
  const float fx0 = bf2f(fx4[0]), fx1 = bf2f(fx4[1]), fx2 = bf2f(fx4[2]), fx3 = bf2f(fx4[3]);
  float fc0 = 0.f, fc1 = 0.f, fc2 = 0.f, fc3 = 0.f;
  for (int q = ofsD[ob + j], e = ofsD[ob + j + 1]; q < e; ++q) {
    const int l = lstD[lb + q];
    const int jr = idr[lb + l], jl = idl[lb + l];
    const u16x4 rv = *(const u16x4*)&ghb[(size_t)(lbase + jr) * NCOLS + 2048 + c];
    const u16x4 lv = *(const u16x4*)&ghb[(size_t)(lbase + jl) * NCOLS + 3072 + c];
    const float4 cc = *(const float4*)&c0[(size_t)(lb + l) * HID + c];
    fc0 += sigmoidf_(fx0 + bf2f(rv[0]) + bf2f(lv[0])) * cc.x;
    fc1 += sigmoidf_(fx1 + bf2f(rv[1]) + bf2f(lv[1])) * cc.y;
    fc2 += sigmoidf_(fx2 + bf2f(rv[2]) + bf2f(lv[2])) * cc.z;
    fc3 += sigmoidf_(fx3 + bf2f(rv[3]) + bf2f(lv[3])) * cc.w;
  }

  const u16x4 vi = *(const u16x4*)&gxb[(size_t)r * NCOLS + c];
  const u16x4 vo = *(const u16x4*)&gxb[(size_t)r * NCOLS + 1024 + c];
  const u16x4 vu = *(const u16x4*)&gxb[(size_t)r * NCOLS + 2048 + c];
  float4 hn, cn;
  {
    const float ig = sigmoidf_(bf2f(vi[0]) + a0), og = sigmoidf_(bf2f(vo[0]));
    cn.x = ig * tanhf(bf2f(vu[0])) + fc0; hn.x = og * tanhf(cn.x);
  }
  {
    const float ig = sigmoidf_(bf2f(vi[1]) + a1), og = sigmoidf_(bf2f(vo[1]));
    cn.y = ig * tanhf(bf2f(vu[1])) + fc1; hn.y = og * tanhf(cn.y);
  }
  {
    const float ig = sigmoidf_(bf2f(vi[2]) + a2), og = sigmoidf_(bf2f(vo[2]));
    cn.z = ig * tanhf(bf2f(vu[2])) + fc2; hn.z = og * tanhf(cn.z);
  }
  {
    const float ig = sigmoidf_(bf2f(vi[3]) + a3), og = sigmoidf_(bf2f(vo[3]));
    cn.w = ig * tanhf(bf2f(vu[3])) + fc3; hn.w = og * tanhf(cn.w);
  }

  if (idd[g] == 0) {
    *(float4*)&hout[(size_t)g * HID + c] = *(const float4*)&h0[(size_t)g * HID + c];
    *(float4*)&cout[(size_t)g * HID + c] = *(const float4*)&c0[(size_t)g * HID + c];
  }
  const int m = *mcount;
  if (g < m) {
    const int o = sel[g];
    *(float4*)&hout[(size_t)o * HID + c] = hn;
    *(float4*)&cout[(size_t)o * HID + c] = cn;
  }
}

extern "C" void kernel_launch(void* const* d_in, const int* in_sizes, int n_in,
                              void* d_out, int out_size, void* d_ws, size_t ws_size,
                              hipStream_t stream) {
  const float* x      = (const float*)d_in[0];
  const float* h0     = (const float*)d_in[1];
  const float* c0     = (const float*)d_in[2];
  const float* W_ioux = (const float*)d_in[3];
  const float* W_iouh = (const float*)d_in[4];
  const float* b_iouh = (const float*)d_in[5];
  const float* W_fx   = (const float*)d_in[6];
  const float* W_fh   = (const float*)d_in[7];
  const float* b_fh   = (const float*)d_in[8];
  const int* idd      = (const int*)d_in[9];
  const int* idr      = (const int*)d_in[10];
  const int* idl      = (const int*)d_in[11];
  float* hout = (float*)d_out;
  float* cout = hout + (size_t)ROWS * HID;

  // fixed region (~17.3 MB)
  char* ws = (char*)d_ws;
  unsigned short* Wxt  = (unsigned short*)(ws);
  unsigned short* Wht  = (unsigned short*)(ws + 8388608u);
  float*          bh   = (float*)(ws + 16777216u);
  int*            sel  = (int*)(ws + 16793600u);
  int*            mcnt = (int*)(ws + 16859136u);
  int*            ofsD = (int*)(ws + 16859392u);
  int*            ofsR = (int*)(ws + 16925184u);
  int*            ofsL = (int*)(ws + 16990976u);
  int*            lstD = (int*)(ws + 17056768u);
  int*            lstR = (int*)(ws + 17122304u);
  int*            lstL = (int*)(ws + 17187840u);
  const size_t    base = 17253376u;

  // chunk size: largest power-of-two divisor of 32 fitting ws (10 MiB per batch)
  int C = 32;
  while (C > 1 && base + 10485760ull * (size_t)C > ws_size) C >>= 1;
  const int R = 512 * C;

  char* p = ws + base;
  unsigned short* xb  = (unsigned short*)p;  p += 1048576ull * C;
  unsigned short* hb  = (unsigned short*)p;  p += 1048576ull * C;
  unsigned short* gxb = (unsigned short*)p;  p += 4194304ull * C;
  unsigned short* ghb = (unsigned short*)p;

  pack_wx<<<dim3(128, 32), dim3(32, 32), 0, stream>>>(W_ioux, W_fx, Wxt);
  pack_wh<<<dim3(128, 32), dim3(32, 32), 0, stream>>>(W_iouh, W_fh, Wht);
  pack_bias<<<4, 1024, 0, stream>>>(b_iouh, b_fh, bh);
  scan_mask<<<1, 1024, 0, stream>>>(idd, sel, mcnt);
  build_csr<<<32, 512, 0, stream>>>(idd, idr, idl, ofsD, ofsR, ofsL, lstD, lstR, lstL);

  for (int b0 = 0; b0 < 32; b0 += C) {
    const size_t r0 = (size_t)b0 * 512;
    convert_bf16<<<R, 256, 0, stream>>>(x + r0 * HID, h0 + r0 * HID, xb, hb);
    gemm8<<<dim3(NCOLS / BN, R / BM, 2), 512, 0, stream>>>(xb, hb, Wxt, Wht, gxb, ghb, bh);
    fused_final<<<R, 256, 0, stream>>>(gxb, ghb, h0, c0, idd, idr, idl,
                                       ofsR, lstR, ofsL, lstL, ofsD, lstD,
                                       sel, mcnt, hout, cout, (int)r0);
  }
}